// Round 9
// baseline (115.764 us; speedup 1.0000x reference)
//
#include <hip/hip_runtime.h>

// Varlen GQA causal attention, v13 = v12 + P-in-register via permuted K staging.
// Key idea: stage key k at LDS row rho(k) = (k&0x23)|((k&0x18)>>1)|((k&4)<<2)
// (swap bit2 with bits4:3). Then S^T element (j,qd,r) scores original key
// 32(j>>1)+8qd+4(j&1)+r, so each lane's 8 pk() words ARE the PV B-fragments
// p0/p1 in natural key order -> the P LDS roundtrip (4 writes + 2 b128 reads +
// 16KB/iter + ~200cy latency) is deleted, and Ps (9.2KB) is freed:
// LDS 27.6 -> 18.4 KB. launch_bounds(256,6) -> 24 waves/CU (VGPR cap 84, safe).
// Causal mask uses the permuted key formula (same cost). V path, O layout,
// epilogue, preconv (coalesced LDS-transpose), staging roles: v12-verbatim.
// S^T = K·(scaled Q)^T, O^T = V^T·P^T  (mfma_f32_16x16x32_bf16).

#define H    16
#define HKV  4
#define D    64
#define BM   16
#define BN   64
#define KSTR 72
#define NEGF (-1e30f)

using bf8 = __attribute__((ext_vector_type(8))) short;
using f4v = __attribute__((ext_vector_type(4))) float;
typedef unsigned int u32;

union bf8u { bf8 v; u32 w[4]; };

// pack two fp32 -> [bf16(b)<<16 | bf16(a)], round-half-up (2 add + 1 perm)
__device__ inline u32 pk(float a, float b) {
    union { float f; u32 u; } x, y; x.f = a; y.f = b;
    return __builtin_amdgcn_perm(y.u + 0x8000u, x.u + 0x8000u, 0x07060302u);
}

#define MFMA(A, B, C) __builtin_amdgcn_mfma_f32_16x16x32_bf16(A, B, C, 0, 0, 0)

// ---------- kernel A: preconvert (coalesced V^T via LDS transpose) ----------
__global__ __launch_bounds__(256)
void preconv(const float* __restrict__ kv, short* __restrict__ Kb,
             short* __restrict__ Vb, int total)
{
    __shared__ u32 Vp[64 * 33];                  // [d][token-pair], stride 33 (pad)

    const int tile = blockIdx.x, kvh = blockIdx.y, t = threadIdx.x;
    const int d4 = t & 15;
    const int T0 = tile * 64;

    // K: [kvh][tok][d], coalesced in and out
    #pragma unroll
    for (int i = 0; i < 4; ++i) {
        int tok = T0 + (t >> 4) + 16 * i;
        if (tok < total) {
            float4 v = *(const float4*)&kv[(size_t)tok * 512 + kvh * 64 + d4 * 4];
            *(uint2*)&Kb[((size_t)kvh * total + tok) * 64 + d4 * 4] =
                make_uint2(pk(v.x, v.y), pk(v.z, v.w));
        }
    }

    if (T0 + 64 <= total) {
        // fast path: pack token-pairs into LDS, write out coalesced
        #pragma unroll
        for (int i = 0; i < 2; ++i) {
            int tp = (t >> 4) + 16 * i;          // token pair 0..31
            int ta = T0 + 2 * tp;
            float4 va = *(const float4*)&kv[(size_t)ta * 512 + (HKV + kvh) * 64 + d4 * 4];
            float4 vb = *(const float4*)&kv[(size_t)(ta + 1) * 512 + (HKV + kvh) * 64 + d4 * 4];
            const float* pa = &va.x; const float* pb = &vb.x;
            #pragma unroll
            for (int j = 0; j < 4; ++j)
                Vp[(4 * d4 + j) * 33 + tp] = pk(pa[j], pb[j]);
        }
        __syncthreads();
        const int d = t >> 2, qq = t & 3;
        u32* dst = (u32*)Vb + ((size_t)kvh * 64 + d) * (total / 2) + T0 / 2 + 8 * qq;
        const u32* src = &Vp[d * 33 + 8 * qq];
        *(uint4*)(dst)     = *(const uint4*)(src);
        *(uint4*)(dst + 4) = *(const uint4*)(src + 4);
    } else {
        // tail tile: scattered path, guarded
        #pragma unroll
        for (int i = 0; i < 2; ++i) {
            int ta = T0 + 2 * ((t >> 4) + 16 * i);
            if (ta < total) {
                int tb = min(ta + 1, total - 1);
                float4 va = *(const float4*)&kv[(size_t)ta * 512 + (HKV + kvh) * 64 + d4 * 4];
                float4 vb = *(const float4*)&kv[(size_t)tb * 512 + (HKV + kvh) * 64 + d4 * 4];
                const float* pa = &va.x; const float* pb = &vb.x;
                #pragma unroll
                for (int j = 0; j < 4; ++j)
                    *(u32*)&Vb[((size_t)kvh * 64 + 4 * d4 + j) * total + ta] = pk(pa[j], pb[j]);
            }
        }
    }
}

// ---------- kernel B: attention ----------
__global__ __launch_bounds__(256, 6)
void attn13(const float* __restrict__ q, const short* __restrict__ Kb,
            const short* __restrict__ Vb, const int* __restrict__ cu,
            float* __restrict__ out, int nb, int total)
{
    __shared__ __attribute__((aligned(16))) short Ks[BN * KSTR];      // [perm key][d]
    __shared__ __attribute__((aligned(16))) short Vt[D * KSTR];       // [d][key]

    const int kvh = blockIdx.y;

    // locate (seq, q-tile); long tiles (high q0) first
    int bid = blockIdx.x, b = -1, start = 0, len = 0, q0 = 0, acc = 0;
    for (int i = 0; i < nb; ++i) {
        int s0 = cu[i], l = cu[i + 1] - s0, nt = (l + BM - 1) / BM;
        if (bid < acc + nt) { b = i; start = s0; len = l; q0 = (nt - 1 - (bid - acc)) * BM; break; }
        acc += nt;
    }
    if (b < 0) return;

    const int t = threadIdx.x, w = t >> 6, lane = t & 63;
    const int qd = lane >> 4, c = lane & 15;
    const int h = kvh * 4 + w;
    const int rows = min(BM, len - q0), kend = q0 + rows;
    const float SC = 0.125f * 1.44269504f;        // scale * log2(e)

    // ---- Q B-fragments straight from global (scaled) ----
    bf8u qf0, qf1;
    {
        int qr = min(c, rows - 1);
        const float* qp = q + (size_t)(start + q0 + qr) * (H * D) + h * D + qd * 8;
        float4 a0 = *(const float4*)qp;
        float4 a1 = *(const float4*)(qp + 4);
        float4 a2 = *(const float4*)(qp + 32);
        float4 a3 = *(const float4*)(qp + 36);
        qf0.w[0] = pk(a0.x * SC, a0.y * SC); qf0.w[1] = pk(a0.z * SC, a0.w * SC);
        qf0.w[2] = pk(a1.x * SC, a1.y * SC); qf0.w[3] = pk(a1.z * SC, a1.w * SC);
        qf1.w[0] = pk(a2.x * SC, a2.y * SC); qf1.w[1] = pk(a2.z * SC, a2.w * SC);
        qf1.w[2] = pk(a3.x * SC, a3.y * SC); qf1.w[3] = pk(a3.z * SC, a3.w * SC);
    }

    // staging roles: row sr (0..63), granules sg and sg+4 (8 bf16 = 16B each)
    const int sr = t >> 2, sg = t & 3;
    // permuted K row: key sr lands at row rho(sr) (swap bit2 <-> bits4:3)
    const int rs = (sr & 0x23) | ((sr & 0x18) >> 1) | ((sr & 4) << 2);
    const short* Kbh = Kb + (size_t)kvh * total * 64;
    const short* Vbh = Vb + (size_t)kvh * 64 * total;
    uint4 kpre0, kpre1, vpre0, vpre1;

    auto prefetch = [&](int kt0) {
        int tok = min(start + kt0 + sr, total - 1);
        const short* kp = Kbh + (size_t)tok * 64 + sg * 8;
        kpre0 = *(const uint4*)(kp);
        kpre1 = *(const uint4*)(kp + 32);
        const short* vp = Vbh + (size_t)sr * total;
        int t0 = min(start + kt0 + 8 * sg, total - 8);       // clamp: OOB keys masked
        int t1 = min(start + kt0 + 8 * sg + 32, total - 8);
        vpre0 = *(const uint4*)(vp + t0);
        vpre1 = *(const uint4*)(vp + t1);
    };

    float l_i = 0.f;
    f4v o0 = {0,0,0,0}, o1 = {0,0,0,0}, o2 = {0,0,0,0}, o3 = {0,0,0,0};

    prefetch(0);

    for (int kt0 = 0; kt0 < kend; kt0 += BN) {
        __syncthreads();                         // prev-iter LDS readers done
        *(uint4*)&Ks[rs * KSTR + sg * 8]      = kpre0;
        *(uint4*)&Ks[rs * KSTR + sg * 8 + 32] = kpre1;
        *(uint4*)&Vt[sr * KSTR + sg * 8]      = vpre0;
        *(uint4*)&Vt[sr * KSTR + sg * 8 + 32] = vpre1;
        __syncthreads();

        if (kt0 + BN < kend) prefetch(kt0 + BN); // overlaps compute below

        // ---- S^T: 4 key-tiles of 16 (rows permuted) ----
        f4v s0 = {0,0,0,0}, s1 = {0,0,0,0}, s2 = {0,0,0,0}, s3 = {0,0,0,0};
        {
            bf8 ka, kb;
            ka = *(const bf8*)&Ks[(c     ) * KSTR + qd * 8];
            kb = *(const bf8*)&Ks[(c     ) * KSTR + 32 + qd * 8];
            s0 = MFMA(ka, qf0.v, s0); s0 = MFMA(kb, qf1.v, s0);
            ka = *(const bf8*)&Ks[(16 + c) * KSTR + qd * 8];
            kb = *(const bf8*)&Ks[(16 + c) * KSTR + 32 + qd * 8];
            s1 = MFMA(ka, qf0.v, s1); s1 = MFMA(kb, qf1.v, s1);
            ka = *(const bf8*)&Ks[(32 + c) * KSTR + qd * 8];
            kb = *(const bf8*)&Ks[(32 + c) * KSTR + 32 + qd * 8];
            s2 = MFMA(ka, qf0.v, s2); s2 = MFMA(kb, qf1.v, s2);
            ka = *(const bf8*)&Ks[(48 + c) * KSTR + qd * 8];
            kb = *(const bf8*)&Ks[(48 + c) * KSTR + 32 + qd * 8];
            s3 = MFMA(ka, qf0.v, s3); s3 = MFMA(kb, qf1.v, s3);
        }

        // ---- no-max softmax; element (j,qd,r) is key 32(j>>1)+8qd+4(j&1)+r ----
        float e[16];
        #pragma unroll
        for (int r = 0; r < 4; ++r) {
            e[r] = s0[r]; e[4 + r] = s1[r]; e[8 + r] = s2[r]; e[12 + r] = s3[r];
        }
        if (kt0 + 63 > q0) {                     // only tiles touching the diagonal
            const int limit = q0 + c - kt0 - 8 * qd;
            #pragma unroll
            for (int j = 0; j < 4; ++j) {
                const int kb_ = 32 * (j >> 1) + 4 * (j & 1);
                #pragma unroll
                for (int r = 0; r < 4; ++r)
                    if (kb_ + r > limit) e[4 * j + r] = NEGF;
            }
        }
        float ls = 0.f;
        #pragma unroll
        for (int i = 0; i < 16; ++i) { e[i] = exp2f(e[i]); ls += e[i]; }
        l_i += ls;

        // ---- P fragments directly in registers (natural key order) ----
        bf8u p0u, p1u;
        p0u.w[0] = pk(e[0],  e[1]);  p0u.w[1] = pk(e[2],  e[3]);
        p0u.w[2] = pk(e[4],  e[5]);  p0u.w[3] = pk(e[6],  e[7]);
        p1u.w[0] = pk(e[8],  e[9]);  p1u.w[1] = pk(e[10], e[11]);
        p1u.w[2] = pk(e[12], e[13]); p1u.w[3] = pk(e[14], e[15]);
        bf8 p0 = p0u.v, p1 = p1u.v;

        // ---- O^T += V^T · P^T ----
        o0 = MFMA(*(const bf8*)&Vt[(c     ) * KSTR + qd * 8],      p0, o0);
        o0 = MFMA(*(const bf8*)&Vt[(c     ) * KSTR + 32 + qd * 8], p1, o0);
        o1 = MFMA(*(const bf8*)&Vt[(16 + c) * KSTR + qd * 8],      p0, o1);
        o1 = MFMA(*(const bf8*)&Vt[(16 + c) * KSTR + 32 + qd * 8], p1, o1);
        o2 = MFMA(*(const bf8*)&Vt[(32 + c) * KSTR + qd * 8],      p0, o2);
        o2 = MFMA(*(const bf8*)&Vt[(32 + c) * KSTR + 32 + qd * 8], p1, o2);
        o3 = MFMA(*(const bf8*)&Vt[(48 + c) * KSTR + qd * 8],      p0, o3);
        o3 = MFMA(*(const bf8*)&Vt[(48 + c) * KSTR + 32 + qd * 8], p1, o3);
    }

    // ---- epilogue: cross-lane l reduction (quads hold disjoint key sets) ----
    if (c < rows) {
        float lt = l_i + __shfl_xor(l_i, 16, 64);
        lt += __shfl_xor(lt, 32, 64);
        const float inv = 1.f / lt;
        float* op = out + (size_t)(start + q0 + c) * (H * D) + h * D + 4 * qd;
        *(float4*)(op)      = make_float4(o0[0] * inv, o0[1] * inv, o0[2] * inv, o0[3] * inv);
        *(float4*)(op + 16) = make_float4(o1[0] * inv, o1[1] * inv, o1[2] * inv, o1[3] * inv);
        *(float4*)(op + 32) = make_float4(o2[0] * inv, o2[1] * inv, o2[2] * inv, o2[3] * inv);
        *(float4*)(op + 48) = make_float4(o3[0] * inv, o3[1] * inv, o3[2] * inv, o3[3] * inv);
    }
}

extern "C" void kernel_launch(void* const* d_in, const int* in_sizes, int n_in,
                              void* d_out, int out_size, void* d_ws, size_t ws_size,
                              hipStream_t stream) {
    const float* q  = (const float*)d_in[0];
    const float* kv = (const float*)d_in[1];
    const int*   cu = (const int*)d_in[2];
    float* out = (float*)d_out;

    const int total = in_sizes[0] / (H * D);
    const int nb    = in_sizes[2] - 1;

    short* Kb = (short*)d_ws;                               // 4*total*64 bf16
    short* Vb = Kb + (size_t)HKV * total * 64;              // 4*total*64 bf16

    dim3 gridA((total + 63) / 64, HKV);
    preconv<<<gridA, 256, 0, stream>>>(kv, Kb, Vb, total);

    const int tile_ub = total / BM + nb;                    // >= sum of ceil(len/BM)
    dim3 gridB(tile_ub, HKV);
    attn13<<<gridB, 256, 0, stream>>>(q, Kb, Vb, cu, out, nb, total);
}

// Round 10
// 115.420 us; speedup vs baseline: 1.0030x; 1.0030x over previous
//
#include <hip/hip_runtime.h>

// Varlen GQA causal attention, v14 = v13 + depth-2 prefetch ring.
// Model (r0-r9 ledger): harness-fixed ~75us; attn ~= the single longest block
// (64 iters, nearly whole grid co-resident at 5 blocks/CU); per-iteration is
// bound by staging-load latency under machine-wide contention (VALUBusy 15%,
// MfmaUtil 6% at ~20 resident waves/CU), NOT by VALU/LDS ops (v13's op-removal
// was neutral). v14 doubles the prefetch pipeline: two register sets A/B,
// tile t+2's loads issue as set-written, giving 2 compute phases (~1600cy) of
// latency cover vs 1 (~800cy). Static reg indexing via 2x-unrolled macro body.
// Kernel A: coalesced preconv (v12). Kernel B: permuted-K in-register P (v13).
// S^T = K·(scaled Q)^T, O^T = V^T·P^T  (mfma_f32_16x16x32_bf16).

#define H    16
#define HKV  4
#define D    64
#define BM   16
#define BN   64
#define KSTR 72
#define NEGF (-1e30f)

using bf8 = __attribute__((ext_vector_type(8))) short;
using f4v = __attribute__((ext_vector_type(4))) float;
typedef unsigned int u32;

union bf8u { bf8 v; u32 w[4]; };

// pack two fp32 -> [bf16(b)<<16 | bf16(a)], round-half-up (2 add + 1 perm)
__device__ inline u32 pk(float a, float b) {
    union { float f; u32 u; } x, y; x.f = a; y.f = b;
    return __builtin_amdgcn_perm(y.u + 0x8000u, x.u + 0x8000u, 0x07060302u);
}

#define MFMA(A, B, C) __builtin_amdgcn_mfma_f32_16x16x32_bf16(A, B, C, 0, 0, 0)

// ---------- kernel A: preconvert (coalesced V^T via LDS transpose) ----------
__global__ __launch_bounds__(256)
void preconv(const float* __restrict__ kv, short* __restrict__ Kb,
             short* __restrict__ Vb, int total)
{
    __shared__ u32 Vp[64 * 33];                  // [d][token-pair], stride 33 (pad)

    const int tile = blockIdx.x, kvh = blockIdx.y, t = threadIdx.x;
    const int d4 = t & 15;
    const int T0 = tile * 64;

    // K: [kvh][tok][d], coalesced in and out
    #pragma unroll
    for (int i = 0; i < 4; ++i) {
        int tok = T0 + (t >> 4) + 16 * i;
        if (tok < total) {
            float4 v = *(const float4*)&kv[(size_t)tok * 512 + kvh * 64 + d4 * 4];
            *(uint2*)&Kb[((size_t)kvh * total + tok) * 64 + d4 * 4] =
                make_uint2(pk(v.x, v.y), pk(v.z, v.w));
        }
    }

    if (T0 + 64 <= total) {
        // fast path: pack token-pairs into LDS, write out coalesced
        #pragma unroll
        for (int i = 0; i < 2; ++i) {
            int tp = (t >> 4) + 16 * i;          // token pair 0..31
            int ta = T0 + 2 * tp;
            float4 va = *(const float4*)&kv[(size_t)ta * 512 + (HKV + kvh) * 64 + d4 * 4];
            float4 vb = *(const float4*)&kv[(size_t)(ta + 1) * 512 + (HKV + kvh) * 64 + d4 * 4];
            const float* pa = &va.x; const float* pb = &vb.x;
            #pragma unroll
            for (int j = 0; j < 4; ++j)
                Vp[(4 * d4 + j) * 33 + tp] = pk(pa[j], pb[j]);
        }
        __syncthreads();
        const int d = t >> 2, qq = t & 3;
        u32* dst = (u32*)Vb + ((size_t)kvh * 64 + d) * (total / 2) + T0 / 2 + 8 * qq;
        const u32* src = &Vp[d * 33 + 8 * qq];
        *(uint4*)(dst)     = *(const uint4*)(src);
        *(uint4*)(dst + 4) = *(const uint4*)(src + 4);
    } else {
        // tail tile: scattered path, guarded
        #pragma unroll
        for (int i = 0; i < 2; ++i) {
            int ta = T0 + 2 * ((t >> 4) + 16 * i);
            if (ta < total) {
                int tb = min(ta + 1, total - 1);
                float4 va = *(const float4*)&kv[(size_t)ta * 512 + (HKV + kvh) * 64 + d4 * 4];
                float4 vb = *(const float4*)&kv[(size_t)tb * 512 + (HKV + kvh) * 64 + d4 * 4];
                const float* pa = &va.x; const float* pb = &vb.x;
                #pragma unroll
                for (int j = 0; j < 4; ++j)
                    *(u32*)&Vb[((size_t)kvh * 64 + 4 * d4 + j) * total + ta] = pk(pa[j], pb[j]);
            }
        }
    }
}

// per-iteration body: stage set, refill set 2 tiles ahead, compute tile kt0.
// (macro so the two prefetch register sets stay statically indexed)
#define ATTN_ITER(PK0, PK1, PV0, PV1)                                          \
    {                                                                          \
        __syncthreads();                         /* prev-iter readers done */  \
        *(uint4*)&Ks[rs * KSTR + sg * 8]      = PK0;                           \
        *(uint4*)&Ks[rs * KSTR + sg * 8 + 32] = PK1;                           \
        *(uint4*)&Vt[sr * KSTR + sg * 8]      = PV0;                           \
        *(uint4*)&Vt[sr * KSTR + sg * 8 + 32] = PV1;                           \
        __syncthreads();                                                       \
        {   /* refill this set 2 tiles ahead (clamped; unused past kend) */    \
            int pt = kt0 + 2 * BN;                                             \
            int tok = min(start + pt + sr, total - 1);                         \
            const short* kp = Kbh + (size_t)tok * 64 + sg * 8;                 \
            PK0 = *(const uint4*)(kp);                                         \
            PK1 = *(const uint4*)(kp + 32);                                    \
            int t0 = min(start + pt + 8 * sg, total - 8);                      \
            int t1 = min(start + pt + 8 * sg + 32, total - 8);                 \
            const short* vp = Vbh + (size_t)sr * total;                        \
            PV0 = *(const uint4*)(vp + t0);                                    \
            PV1 = *(const uint4*)(vp + t1);                                    \
        }                                                                      \
        /* ---- S^T: 4 key-tiles of 16 (rows permuted) ---- */                 \
        f4v s0 = {0,0,0,0}, s1 = {0,0,0,0}, s2 = {0,0,0,0}, s3 = {0,0,0,0};    \
        {                                                                      \
            bf8 ka, kb;                                                        \
            ka = *(const bf8*)&Ks[(c     ) * KSTR + qd * 8];                   \
            kb = *(const bf8*)&Ks[(c     ) * KSTR + 32 + qd * 8];              \
            s0 = MFMA(ka, qf0.v, s0); s0 = MFMA(kb, qf1.v, s0);                \
            ka = *(const bf8*)&Ks[(16 + c) * KSTR + qd * 8];                   \
            kb = *(const bf8*)&Ks[(16 + c) * KSTR + 32 + qd * 8];              \
            s1 = MFMA(ka, qf0.v, s1); s1 = MFMA(kb, qf1.v, s1);                \
            ka = *(const bf8*)&Ks[(32 + c) * KSTR + qd * 8];                   \
            kb = *(const bf8*)&Ks[(32 + c) * KSTR + 32 + qd * 8];              \
            s2 = MFMA(ka, qf0.v, s2); s2 = MFMA(kb, qf1.v, s2);                \
            ka = *(const bf8*)&Ks[(48 + c) * KSTR + qd * 8];                   \
            kb = *(const bf8*)&Ks[(48 + c) * KSTR + 32 + qd * 8];              \
            s3 = MFMA(ka, qf0.v, s3); s3 = MFMA(kb, qf1.v, s3);                \
        }                                                                      \
        /* element (j,qd,r) is key 32(j>>1)+8qd+4(j&1)+r */                    \
        float e[16];                                                           \
        _Pragma("unroll")                                                      \
        for (int r = 0; r < 4; ++r) {                                          \
            e[r] = s0[r]; e[4 + r] = s1[r]; e[8 + r] = s2[r]; e[12 + r] = s3[r];\
        }                                                                      \
        if (kt0 + 63 > q0) {                                                   \
            const int limit = q0 + c - kt0 - 8 * qd;                           \
            _Pragma("unroll")                                                  \
            for (int j = 0; j < 4; ++j) {                                      \
                const int kb_ = 32 * (j >> 1) + 4 * (j & 1);                   \
                _Pragma("unroll")                                              \
                for (int r = 0; r < 4; ++r)                                    \
                    if (kb_ + r > limit) e[4 * j + r] = NEGF;                  \
            }                                                                  \
        }                                                                      \
        float ls = 0.f;                                                        \
        _Pragma("unroll")                                                      \
        for (int i = 0; i < 16; ++i) { e[i] = exp2f(e[i]); ls += e[i]; }       \
        l_i += ls;                                                             \
        /* P fragments directly in registers (natural key order) */            \
        bf8u p0u, p1u;                                                         \
        p0u.w[0] = pk(e[0],  e[1]);  p0u.w[1] = pk(e[2],  e[3]);               \
        p0u.w[2] = pk(e[4],  e[5]);  p0u.w[3] = pk(e[6],  e[7]);               \
        p1u.w[0] = pk(e[8],  e[9]);  p1u.w[1] = pk(e[10], e[11]);              \
        p1u.w[2] = pk(e[12], e[13]); p1u.w[3] = pk(e[14], e[15]);              \
        bf8 p0 = p0u.v, p1 = p1u.v;                                            \
        /* O^T += V^T · P^T */                                                 \
        o0 = MFMA(*(const bf8*)&Vt[(c     ) * KSTR + qd * 8],      p0, o0);    \
        o0 = MFMA(*(const bf8*)&Vt[(c     ) * KSTR + 32 + qd * 8], p1, o0);    \
        o1 = MFMA(*(const bf8*)&Vt[(16 + c) * KSTR + qd * 8],      p0, o1);    \
        o1 = MFMA(*(const bf8*)&Vt[(16 + c) * KSTR + 32 + qd * 8], p1, o1);    \
        o2 = MFMA(*(const bf8*)&Vt[(32 + c) * KSTR + qd * 8],      p0, o2);    \
        o2 = MFMA(*(const bf8*)&Vt[(32 + c) * KSTR + 32 + qd * 8], p1, o2);    \
        o3 = MFMA(*(const bf8*)&Vt[(48 + c) * KSTR + qd * 8],      p0, o3);    \
        o3 = MFMA(*(const bf8*)&Vt[(48 + c) * KSTR + 32 + qd * 8], p1, o3);    \
    }

// ---------- kernel B: attention ----------
__global__ __launch_bounds__(256, 5)
void attn14(const float* __restrict__ q, const short* __restrict__ Kb,
            const short* __restrict__ Vb, const int* __restrict__ cu,
            float* __restrict__ out, int nb, int total)
{
    __shared__ __attribute__((aligned(16))) short Ks[BN * KSTR];      // [perm key][d]
    __shared__ __attribute__((aligned(16))) short Vt[D * KSTR];       // [d][key]

    const int kvh = blockIdx.y;

    // locate (seq, q-tile); long tiles (high q0) first
    int bid = blockIdx.x, b = -1, start = 0, len = 0, q0 = 0, acc = 0;
    for (int i = 0; i < nb; ++i) {
        int s0 = cu[i], l = cu[i + 1] - s0, nt = (l + BM - 1) / BM;
        if (bid < acc + nt) { b = i; start = s0; len = l; q0 = (nt - 1 - (bid - acc)) * BM; break; }
        acc += nt;
    }
    if (b < 0) return;

    const int t = threadIdx.x, w = t >> 6, lane = t & 63;
    const int qd = lane >> 4, c = lane & 15;
    const int h = kvh * 4 + w;
    const int rows = min(BM, len - q0), kend = q0 + rows;
    const float SC = 0.125f * 1.44269504f;        // scale * log2(e)

    // ---- Q B-fragments straight from global (scaled) ----
    bf8u qf0, qf1;
    {
        int qr = min(c, rows - 1);
        const float* qp = q + (size_t)(start + q0 + qr) * (H * D) + h * D + qd * 8;
        float4 a0 = *(const float4*)qp;
        float4 a1 = *(const float4*)(qp + 4);
        float4 a2 = *(const float4*)(qp + 32);
        float4 a3 = *(const float4*)(qp + 36);
        qf0.w[0] = pk(a0.x * SC, a0.y * SC); qf0.w[1] = pk(a0.z * SC, a0.w * SC);
        qf0.w[2] = pk(a1.x * SC, a1.y * SC); qf0.w[3] = pk(a1.z * SC, a1.w * SC);
        qf1.w[0] = pk(a2.x * SC, a2.y * SC); qf1.w[1] = pk(a2.z * SC, a2.w * SC);
        qf1.w[2] = pk(a3.x * SC, a3.y * SC); qf1.w[3] = pk(a3.z * SC, a3.w * SC);
    }

    // staging roles: row sr (0..63), granules sg and sg+4 (8 bf16 = 16B each)
    const int sr = t >> 2, sg = t & 3;
    // permuted K row: key sr lands at row rho(sr) (swap bit2 <-> bits4:3)
    const int rs = (sr & 0x23) | ((sr & 0x18) >> 1) | ((sr & 4) << 2);
    const short* Kbh = Kb + (size_t)kvh * total * 64;
    const short* Vbh = Vb + (size_t)kvh * 64 * total;

    // two prefetch register sets (depth-2 ring)
    uint4 kpA0, kpA1, vpA0, vpA1;
    uint4 kpB0, kpB1, vpB0, vpB1;
    {
        int tok = min(start + sr, total - 1);
        const short* kp = Kbh + (size_t)tok * 64 + sg * 8;
        kpA0 = *(const uint4*)(kp);
        kpA1 = *(const uint4*)(kp + 32);
        int t0 = min(start + 8 * sg, total - 8);
        int t1 = min(start + 8 * sg + 32, total - 8);
        const short* vp = Vbh + (size_t)sr * total;
        vpA0 = *(const uint4*)(vp + t0);
        vpA1 = *(const uint4*)(vp + t1);
    }
    {
        int tok = min(start + BN + sr, total - 1);
        const short* kp = Kbh + (size_t)tok * 64 + sg * 8;
        kpB0 = *(const uint4*)(kp);
        kpB1 = *(const uint4*)(kp + 32);
        int t0 = min(start + BN + 8 * sg, total - 8);
        int t1 = min(start + BN + 8 * sg + 32, total - 8);
        const short* vp = Vbh + (size_t)sr * total;
        vpB0 = *(const uint4*)(vp + t0);
        vpB1 = *(const uint4*)(vp + t1);
    }

    float l_i = 0.f;
    f4v o0 = {0,0,0,0}, o1 = {0,0,0,0}, o2 = {0,0,0,0}, o3 = {0,0,0,0};

    int kt0 = 0;
    for (;;) {
        ATTN_ITER(kpA0, kpA1, vpA0, vpA1)
        kt0 += BN; if (kt0 >= kend) break;
        ATTN_ITER(kpB0, kpB1, vpB0, vpB1)
        kt0 += BN; if (kt0 >= kend) break;
    }

    // ---- epilogue: cross-lane l reduction (quads hold disjoint key sets) ----
    if (c < rows) {
        float lt = l_i + __shfl_xor(l_i, 16, 64);
        lt += __shfl_xor(lt, 32, 64);
        const float inv = 1.f / lt;
        float* op = out + (size_t)(start + q0 + c) * (H * D) + h * D + 4 * qd;
        *(float4*)(op)      = make_float4(o0[0] * inv, o0[1] * inv, o0[2] * inv, o0[3] * inv);
        *(float4*)(op + 16) = make_float4(o1[0] * inv, o1[1] * inv, o1[2] * inv, o1[3] * inv);
        *(float4*)(op + 32) = make_float4(o2[0] * inv, o2[1] * inv, o2[2] * inv, o2[3] * inv);
        *(float4*)(op + 48) = make_float4(o3[0] * inv, o3[1] * inv, o3[2] * inv, o3[3] * inv);
    }
}

extern "C" void kernel_launch(void* const* d_in, const int* in_sizes, int n_in,
                              void* d_out, int out_size, void* d_ws, size_t ws_size,
                              hipStream_t stream) {
    const float* q  = (const float*)d_in[0];
    const float* kv = (const float*)d_in[1];
    const int*   cu = (const int*)d_in[2];
    float* out = (float*)d_out;

    const int total = in_sizes[0] / (H * D);
    const int nb    = in_sizes[2] - 1;

    short* Kb = (short*)d_ws;                               // 4*total*64 bf16
    short* Vb = Kb + (size_t)HKV * total * 64;              // 4*total*64 bf16

    dim3 gridA((total + 63) / 64, HKV);
    preconv<<<gridA, 256, 0, stream>>>(kv, Kb, Vb, total);

    const int tile_ub = total / BM + nb;                    // >= sum of ceil(len/BM)
    dim3 gridB(tile_ub, HKV);
    attn14<<<gridB, 256, 0, stream>>>(q, Kb, Vb, cu, out, nb, total);
}

// Round 11
// 114.101 us; speedup vs baseline: 1.0146x; 1.0116x over previous
//
#include <hip/hip_runtime.h>

// Varlen GQA causal attention, v15 = v14 + counted-vmcnt barriers.
// Diagnosis: v5/v13/v14 (3 structurally different inner loops) all ~38us attn
// -> bound by the one shared mechanism: __syncthreads() drains vmcnt(0)
// (m97 evidence), forcing prefetch loads complete every iteration; ring depth
// was irrelevant. v15 replaces both __syncthreads with
// {s_waitcnt lgkmcnt(0); s_barrier} (raw builtin, NO vmcnt drain). Register
// dependency tracking still emits counted vmcnt(N) at the staging ds_writes,
// so the depth-2 ring's loads (issued 2 iters ago) get ~1700cy of cover and
// the other set's loads stay in flight across barriers (T4: never vmcnt(0)
// in the main loop). lgkmcnt(0) before each barrier keeps LDS r/w visibility
// correct across waves. Everything else v14-verbatim.
// S^T = K·(scaled Q)^T, O^T = V^T·P^T  (mfma_f32_16x16x32_bf16).

#define H    16
#define HKV  4
#define D    64
#define BM   16
#define BN   64
#define KSTR 72
#define NEGF (-1e30f)

using bf8 = __attribute__((ext_vector_type(8))) short;
using f4v = __attribute__((ext_vector_type(4))) float;
typedef unsigned int u32;

union bf8u { bf8 v; u32 w[4]; };

// pack two fp32 -> [bf16(b)<<16 | bf16(a)], round-half-up (2 add + 1 perm)
__device__ inline u32 pk(float a, float b) {
    union { float f; u32 u; } x, y; x.f = a; y.f = b;
    return __builtin_amdgcn_perm(y.u + 0x8000u, x.u + 0x8000u, 0x07060302u);
}

#define MFMA(A, B, C) __builtin_amdgcn_mfma_f32_16x16x32_bf16(A, B, C, 0, 0, 0)

// workgroup barrier WITHOUT the vmcnt(0) drain: own LDS ops visible, then
// raw s_barrier; prefetch global loads stay in flight (counted waits at use).
#define BARRIER_NOVM()                                         \
    asm volatile("s_waitcnt lgkmcnt(0)" ::: "memory");         \
    __builtin_amdgcn_s_barrier();                              \
    asm volatile("" ::: "memory");

// ---------- kernel A: preconvert (coalesced V^T via LDS transpose) ----------
__global__ __launch_bounds__(256)
void preconv(const float* __restrict__ kv, short* __restrict__ Kb,
             short* __restrict__ Vb, int total)
{
    __shared__ u32 Vp[64 * 33];                  // [d][token-pair], stride 33 (pad)

    const int tile = blockIdx.x, kvh = blockIdx.y, t = threadIdx.x;
    const int d4 = t & 15;
    const int T0 = tile * 64;

    // K: [kvh][tok][d], coalesced in and out
    #pragma unroll
    for (int i = 0; i < 4; ++i) {
        int tok = T0 + (t >> 4) + 16 * i;
        if (tok < total) {
            float4 v = *(const float4*)&kv[(size_t)tok * 512 + kvh * 64 + d4 * 4];
            *(uint2*)&Kb[((size_t)kvh * total + tok) * 64 + d4 * 4] =
                make_uint2(pk(v.x, v.y), pk(v.z, v.w));
        }
    }

    if (T0 + 64 <= total) {
        // fast path: pack token-pairs into LDS, write out coalesced
        #pragma unroll
        for (int i = 0; i < 2; ++i) {
            int tp = (t >> 4) + 16 * i;          // token pair 0..31
            int ta = T0 + 2 * tp;
            float4 va = *(const float4*)&kv[(size_t)ta * 512 + (HKV + kvh) * 64 + d4 * 4];
            float4 vb = *(const float4*)&kv[(size_t)(ta + 1) * 512 + (HKV + kvh) * 64 + d4 * 4];
            const float* pa = &va.x; const float* pb = &vb.x;
            #pragma unroll
            for (int j = 0; j < 4; ++j)
                Vp[(4 * d4 + j) * 33 + tp] = pk(pa[j], pb[j]);
        }
        __syncthreads();
        const int d = t >> 2, qq = t & 3;
        u32* dst = (u32*)Vb + ((size_t)kvh * 64 + d) * (total / 2) + T0 / 2 + 8 * qq;
        const u32* src = &Vp[d * 33 + 8 * qq];
        *(uint4*)(dst)     = *(const uint4*)(src);
        *(uint4*)(dst + 4) = *(const uint4*)(src + 4);
    } else {
        // tail tile: scattered path, guarded
        #pragma unroll
        for (int i = 0; i < 2; ++i) {
            int ta = T0 + 2 * ((t >> 4) + 16 * i);
            if (ta < total) {
                int tb = min(ta + 1, total - 1);
                float4 va = *(const float4*)&kv[(size_t)ta * 512 + (HKV + kvh) * 64 + d4 * 4];
                float4 vb = *(const float4*)&kv[(size_t)tb * 512 + (HKV + kvh) * 64 + d4 * 4];
                const float* pa = &va.x; const float* pb = &vb.x;
                #pragma unroll
                for (int j = 0; j < 4; ++j)
                    *(u32*)&Vb[((size_t)kvh * 64 + 4 * d4 + j) * total + ta] = pk(pa[j], pb[j]);
            }
        }
    }
}

// per-iteration body: stage set, refill set 2 tiles ahead, compute tile kt0.
// (macro so the two prefetch register sets stay statically indexed)
#define ATTN_ITER(PK0, PK1, PV0, PV1)                                          \
    {                                                                          \
        BARRIER_NOVM()                           /* prev-iter readers done */  \
        *(uint4*)&Ks[rs * KSTR + sg * 8]      = PK0;                           \
        *(uint4*)&Ks[rs * KSTR + sg * 8 + 32] = PK1;                           \
        *(uint4*)&Vt[sr * KSTR + sg * 8]      = PV0;                           \
        *(uint4*)&Vt[sr * KSTR + sg * 8 + 32] = PV1;                           \
        BARRIER_NOVM()                           /* staging visible */         \
        {   /* refill this set 2 tiles ahead (clamped; unused past kend) */    \
            int pt = kt0 + 2 * BN;                                             \
            int tok = min(start + pt + sr, total - 1);                         \
            const short* kp = Kbh + (size_t)tok * 64 + sg * 8;                 \
            PK0 = *(const uint4*)(kp);                                         \
            PK1 = *(const uint4*)(kp + 32);                                    \
            int t0 = min(start + pt + 8 * sg, total - 8);                      \
            int t1 = min(start + pt + 8 * sg + 32, total - 8);                 \
            const short* vp = Vbh + (size_t)sr * total;                        \
            PV0 = *(const uint4*)(vp + t0);                                    \
            PV1 = *(const uint4*)(vp + t1);                                    \
        }                                                                      \
        /* ---- S^T: 4 key-tiles of 16 (rows permuted) ---- */                 \
        f4v s0 = {0,0,0,0}, s1 = {0,0,0,0}, s2 = {0,0,0,0}, s3 = {0,0,0,0};    \
        {                                                                      \
            bf8 ka, kb;                                                        \
            ka = *(const bf8*)&Ks[(c     ) * KSTR + qd * 8];                   \
            kb = *(const bf8*)&Ks[(c     ) * KSTR + 32 + qd * 8];              \
            s0 = MFMA(ka, qf0.v, s0); s0 = MFMA(kb, qf1.v, s0);                \
            ka = *(const bf8*)&Ks[(16 + c) * KSTR + qd * 8];                   \
            kb = *(const bf8*)&Ks[(16 + c) * KSTR + 32 + qd * 8];              \
            s1 = MFMA(ka, qf0.v, s1); s1 = MFMA(kb, qf1.v, s1);                \
            ka = *(const bf8*)&Ks[(32 + c) * KSTR + qd * 8];                   \
            kb = *(const bf8*)&Ks[(32 + c) * KSTR + 32 + qd * 8];              \
            s2 = MFMA(ka, qf0.v, s2); s2 = MFMA(kb, qf1.v, s2);                \
            ka = *(const bf8*)&Ks[(48 + c) * KSTR + qd * 8];                   \
            kb = *(const bf8*)&Ks[(48 + c) * KSTR + 32 + qd * 8];              \
            s3 = MFMA(ka, qf0.v, s3); s3 = MFMA(kb, qf1.v, s3);                \
        }                                                                      \
        /* element (j,qd,r) is key 32(j>>1)+8qd+4(j&1)+r */                    \
        float e[16];                                                           \
        _Pragma("unroll")                                                      \
        for (int r = 0; r < 4; ++r) {                                          \
            e[r] = s0[r]; e[4 + r] = s1[r]; e[8 + r] = s2[r]; e[12 + r] = s3[r];\
        }                                                                      \
        if (kt0 + 63 > q0) {                                                   \
            const int limit = q0 + c - kt0 - 8 * qd;                           \
            _Pragma("unroll")                                                  \
            for (int j = 0; j < 4; ++j) {                                      \
                const int kb_ = 32 * (j >> 1) + 4 * (j & 1);                   \
                _Pragma("unroll")                                              \
                for (int r = 0; r < 4; ++r)                                    \
                    if (kb_ + r > limit) e[4 * j + r] = NEGF;                  \
            }                                                                  \
        }                                                                      \
        float ls = 0.f;                                                        \
        _Pragma("unroll")                                                      \
        for (int i = 0; i < 16; ++i) { e[i] = exp2f(e[i]); ls += e[i]; }       \
        l_i += ls;                                                             \
        /* P fragments directly in registers (natural key order) */            \
        bf8u p0u, p1u;                                                         \
        p0u.w[0] = pk(e[0],  e[1]);  p0u.w[1] = pk(e[2],  e[3]);               \
        p0u.w[2] = pk(e[4],  e[5]);  p0u.w[3] = pk(e[6],  e[7]);               \
        p1u.w[0] = pk(e[8],  e[9]);  p1u.w[1] = pk(e[10], e[11]);              \
        p1u.w[2] = pk(e[12], e[13]); p1u.w[3] = pk(e[14], e[15]);              \
        bf8 p0 = p0u.v, p1 = p1u.v;                                            \
        /* O^T += V^T · P^T */                                                 \
        o0 = MFMA(*(const bf8*)&Vt[(c     ) * KSTR + qd * 8],      p0, o0);    \
        o0 = MFMA(*(const bf8*)&Vt[(c     ) * KSTR + 32 + qd * 8], p1, o0);    \
        o1 = MFMA(*(const bf8*)&Vt[(16 + c) * KSTR + qd * 8],      p0, o1);    \
        o1 = MFMA(*(const bf8*)&Vt[(16 + c) * KSTR + 32 + qd * 8], p1, o1);    \
        o2 = MFMA(*(const bf8*)&Vt[(32 + c) * KSTR + qd * 8],      p0, o2);    \
        o2 = MFMA(*(const bf8*)&Vt[(32 + c) * KSTR + 32 + qd * 8], p1, o2);    \
        o3 = MFMA(*(const bf8*)&Vt[(48 + c) * KSTR + qd * 8],      p0, o3);    \
        o3 = MFMA(*(const bf8*)&Vt[(48 + c) * KSTR + 32 + qd * 8], p1, o3);    \
    }

// ---------- kernel B: attention ----------
__global__ __launch_bounds__(256, 5)
void attn15(const float* __restrict__ q, const short* __restrict__ Kb,
            const short* __restrict__ Vb, const int* __restrict__ cu,
            float* __restrict__ out, int nb, int total)
{
    __shared__ __attribute__((aligned(16))) short Ks[BN * KSTR];      // [perm key][d]
    __shared__ __attribute__((aligned(16))) short Vt[D * KSTR];       // [d][key]

    const int kvh = blockIdx.y;

    // locate (seq, q-tile); long tiles (high q0) first
    int bid = blockIdx.x, b = -1, start = 0, len = 0, q0 = 0, acc = 0;
    for (int i = 0; i < nb; ++i) {
        int s0 = cu[i], l = cu[i + 1] - s0, nt = (l + BM - 1) / BM;
        if (bid < acc + nt) { b = i; start = s0; len = l; q0 = (nt - 1 - (bid - acc)) * BM; break; }
        acc += nt;
    }
    if (b < 0) return;

    const int t = threadIdx.x, w = t >> 6, lane = t & 63;
    const int qd = lane >> 4, c = lane & 15;
    const int h = kvh * 4 + w;
    const int rows = min(BM, len - q0), kend = q0 + rows;
    const float SC = 0.125f * 1.44269504f;        // scale * log2(e)

    // ---- Q B-fragments straight from global (scaled) ----
    bf8u qf0, qf1;
    {
        int qr = min(c, rows - 1);
        const float* qp = q + (size_t)(start + q0 + qr) * (H * D) + h * D + qd * 8;
        float4 a0 = *(const float4*)qp;
        float4 a1 = *(const float4*)(qp + 4);
        float4 a2 = *(const float4*)(qp + 32);
        float4 a3 = *(const float4*)(qp + 36);
        qf0.w[0] = pk(a0.x * SC, a0.y * SC); qf0.w[1] = pk(a0.z * SC, a0.w * SC);
        qf0.w[2] = pk(a1.x * SC, a1.y * SC); qf0.w[3] = pk(a1.z * SC, a1.w * SC);
        qf1.w[0] = pk(a2.x * SC, a2.y * SC); qf1.w[1] = pk(a2.z * SC, a2.w * SC);
        qf1.w[2] = pk(a3.x * SC, a3.y * SC); qf1.w[3] = pk(a3.z * SC, a3.w * SC);
    }

    // staging roles: row sr (0..63), granules sg and sg+4 (8 bf16 = 16B each)
    const int sr = t >> 2, sg = t & 3;
    // permuted K row: key sr lands at row rho(sr) (swap bit2 <-> bits4:3)
    const int rs = (sr & 0x23) | ((sr & 0x18) >> 1) | ((sr & 4) << 2);
    const short* Kbh = Kb + (size_t)kvh * total * 64;
    const short* Vbh = Vb + (size_t)kvh * 64 * total;

    // two prefetch register sets (depth-2 ring)
    uint4 kpA0, kpA1, vpA0, vpA1;
    uint4 kpB0, kpB1, vpB0, vpB1;
    {
        int tok = min(start + sr, total - 1);
        const short* kp = Kbh + (size_t)tok * 64 + sg * 8;
        kpA0 = *(const uint4*)(kp);
        kpA1 = *(const uint4*)(kp + 32);
        int t0 = min(start + 8 * sg, total - 8);
        int t1 = min(start + 8 * sg + 32, total - 8);
        const short* vp = Vbh + (size_t)sr * total;
        vpA0 = *(const uint4*)(vp + t0);
        vpA1 = *(const uint4*)(vp + t1);
    }
    {
        int tok = min(start + BN + sr, total - 1);
        const short* kp = Kbh + (size_t)tok * 64 + sg * 8;
        kpB0 = *(const uint4*)(kp);
        kpB1 = *(const uint4*)(kp + 32);
        int t0 = min(start + BN + 8 * sg, total - 8);
        int t1 = min(start + BN + 8 * sg + 32, total - 8);
        const short* vp = Vbh + (size_t)sr * total;
        vpB0 = *(const uint4*)(vp + t0);
        vpB1 = *(const uint4*)(vp + t1);
    }

    float l_i = 0.f;
    f4v o0 = {0,0,0,0}, o1 = {0,0,0,0}, o2 = {0,0,0,0}, o3 = {0,0,0,0};

    int kt0 = 0;
    for (;;) {
        ATTN_ITER(kpA0, kpA1, vpA0, vpA1)
        kt0 += BN; if (kt0 >= kend) break;
        ATTN_ITER(kpB0, kpB1, vpB0, vpB1)
        kt0 += BN; if (kt0 >= kend) break;
    }

    // ---- epilogue: cross-lane l reduction (quads hold disjoint key sets) ----
    if (c < rows) {
        float lt = l_i + __shfl_xor(l_i, 16, 64);
        lt += __shfl_xor(lt, 32, 64);
        const float inv = 1.f / lt;
        float* op = out + (size_t)(start + q0 + c) * (H * D) + h * D + 4 * qd;
        *(float4*)(op)      = make_float4(o0[0] * inv, o0[1] * inv, o0[2] * inv, o0[3] * inv);
        *(float4*)(op + 16) = make_float4(o1[0] * inv, o1[1] * inv, o1[2] * inv, o1[3] * inv);
        *(float4*)(op + 32) = make_float4(o2[0] * inv, o2[1] * inv, o2[2] * inv, o2[3] * inv);
        *(float4*)(op + 48) = make_float4(o3[0] * inv, o3[1] * inv, o3[2] * inv, o3[3] * inv);
    }
}

extern "C" void kernel_launch(void* const* d_in, const int* in_sizes, int n_in,
                              void* d_out, int out_size, void* d_ws, size_t ws_size,
                              hipStream_t stream) {
    const float* q  = (const float*)d_in[0];
    const float* kv = (const float*)d_in[1];
    const int*   cu = (const int*)d_in[2];
    float* out = (float*)d_out;

    const int total = in_sizes[0] / (H * D);
    const int nb    = in_sizes[2] - 1;

    short* Kb = (short*)d_ws;                               // 4*total*64 bf16
    short* Vb = Kb + (size_t)HKV * total * 64;              // 4*total*64 bf16

    dim3 gridA((total + 63) / 64, HKV);
    preconv<<<gridA, 256, 0, stream>>>(kv, Kb, Vb, total);

    const int tile_ub = total / BM + nb;                    // >= sum of ceil(len/BM)
    dim3 gridB(tile_ub, HKV);
    attn15<<<gridB, 256, 0, stream>>>(q, Kb, Vb, cu, out, nb, total);
}

// Round 12
// 113.352 us; speedup vs baseline: 1.0213x; 1.0066x over previous
//
#include <hip/hip_runtime.h>

// Varlen GQA causal attention, v16 = v15 + double-buffered LDS, 1 barrier/iter,
// setprio on MFMA clusters.
// r8-r11: five structurally different inner loops all ~33us attn. Shared trait:
// single-buffered LDS -> same-iteration staging->compute dependency fenced by
// TWO barriers. v16: compute tile t from buf[p] while staging tile t+1 into
// buf[p^1]; single BARRIER_NOVM (lgkmcnt(0)+s_barrier, no vmcnt drain) per
// iter. Race-safe: buf[p^1] readers finished before prev iter's end barrier
// (lgkmcnt0 covers own reads); buf[p] writers act only after this iter's end
// barrier. A/B reg ring keeps load->stage distance = 2 iters (refill kt0+3BN);
// ds_write->ds_read gap becomes a full iteration. LDS 36.9KB -> 4 blocks/CU.
// T5: s_setprio(1) around the two 8-MFMA clusters (+4-7% attn in learn_hip).
// Kernel A: coalesced preconv (v12). P-in-register via permuted K rows (v13).
// S^T = K·(scaled Q)^T, O^T = V^T·P^T  (mfma_f32_16x16x32_bf16).

#define H    16
#define HKV  4
#define D    64
#define BM   16
#define BN   64
#define KSTR 72
#define NEGF (-1e30f)

using bf8 = __attribute__((ext_vector_type(8))) short;
using f4v = __attribute__((ext_vector_type(4))) float;
typedef unsigned int u32;

union bf8u { bf8 v; u32 w[4]; };

// pack two fp32 -> [bf16(b)<<16 | bf16(a)], round-half-up (2 add + 1 perm)
__device__ inline u32 pk(float a, float b) {
    union { float f; u32 u; } x, y; x.f = a; y.f = b;
    return __builtin_amdgcn_perm(y.u + 0x8000u, x.u + 0x8000u, 0x07060302u);
}

#define MFMA(A, B, C) __builtin_amdgcn_mfma_f32_16x16x32_bf16(A, B, C, 0, 0, 0)

// workgroup barrier WITHOUT the vmcnt(0) drain: own LDS ops visible, then
// raw s_barrier; prefetch global loads stay in flight (counted waits at use).
#define BARRIER_NOVM()                                         \
    asm volatile("s_waitcnt lgkmcnt(0)" ::: "memory");         \
    __builtin_amdgcn_s_barrier();                              \
    asm volatile("" ::: "memory");

// ---------- kernel A: preconvert (coalesced V^T via LDS transpose) ----------
__global__ __launch_bounds__(256)
void preconv(const float* __restrict__ kv, short* __restrict__ Kb,
             short* __restrict__ Vb, int total)
{
    __shared__ u32 Vp[64 * 33];                  // [d][token-pair], stride 33 (pad)

    const int tile = blockIdx.x, kvh = blockIdx.y, t = threadIdx.x;
    const int d4 = t & 15;
    const int T0 = tile * 64;

    // K: [kvh][tok][d], coalesced in and out
    #pragma unroll
    for (int i = 0; i < 4; ++i) {
        int tok = T0 + (t >> 4) + 16 * i;
        if (tok < total) {
            float4 v = *(const float4*)&kv[(size_t)tok * 512 + kvh * 64 + d4 * 4];
            *(uint2*)&Kb[((size_t)kvh * total + tok) * 64 + d4 * 4] =
                make_uint2(pk(v.x, v.y), pk(v.z, v.w));
        }
    }

    if (T0 + 64 <= total) {
        // fast path: pack token-pairs into LDS, write out coalesced
        #pragma unroll
        for (int i = 0; i < 2; ++i) {
            int tp = (t >> 4) + 16 * i;          // token pair 0..31
            int ta = T0 + 2 * tp;
            float4 va = *(const float4*)&kv[(size_t)ta * 512 + (HKV + kvh) * 64 + d4 * 4];
            float4 vb = *(const float4*)&kv[(size_t)(ta + 1) * 512 + (HKV + kvh) * 64 + d4 * 4];
            const float* pa = &va.x; const float* pb = &vb.x;
            #pragma unroll
            for (int j = 0; j < 4; ++j)
                Vp[(4 * d4 + j) * 33 + tp] = pk(pa[j], pb[j]);
        }
        __syncthreads();
        const int d = t >> 2, qq = t & 3;
        u32* dst = (u32*)Vb + ((size_t)kvh * 64 + d) * (total / 2) + T0 / 2 + 8 * qq;
        const u32* src = &Vp[d * 33 + 8 * qq];
        *(uint4*)(dst)     = *(const uint4*)(src);
        *(uint4*)(dst + 4) = *(const uint4*)(src + 4);
    } else {
        // tail tile: scattered path, guarded
        #pragma unroll
        for (int i = 0; i < 2; ++i) {
            int ta = T0 + 2 * ((t >> 4) + 16 * i);
            if (ta < total) {
                int tb = min(ta + 1, total - 1);
                float4 va = *(const float4*)&kv[(size_t)ta * 512 + (HKV + kvh) * 64 + d4 * 4];
                float4 vb = *(const float4*)&kv[(size_t)tb * 512 + (HKV + kvh) * 64 + d4 * 4];
                const float* pa = &va.x; const float* pb = &vb.x;
                #pragma unroll
                for (int j = 0; j < 4; ++j)
                    *(u32*)&Vb[((size_t)kvh * 64 + 4 * d4 + j) * total + ta] = pk(pa[j], pb[j]);
            }
        }
    }
}

// per-iteration body: stage tile kt0+BN into write bufs from reg set, refill
// set with tile kt0+3BN, compute tile kt0 from read bufs, one barrier.
// (macro: all buffer pointers and reg-set members statically indexed)
#define ATTN_ITER(KR, VR, KW, VW, PK0, PK1, PV0, PV1)                          \
    {                                                                          \
        /* stage next tile into write buffers (readers done last iter) */      \
        *(uint4*)&KW[rs * KSTR + sg * 8]      = PK0;                           \
        *(uint4*)&KW[rs * KSTR + sg * 8 + 32] = PK1;                           \
        *(uint4*)&VW[sr * KSTR + sg * 8]      = PV0;                           \
        *(uint4*)&VW[sr * KSTR + sg * 8 + 32] = PV1;                           \
        {   /* refill this set 3 tiles ahead (clamped; unused past kend) */    \
            int pt = kt0 + 3 * BN;                                             \
            int tok = min(start + pt + sr, total - 1);                         \
            const short* kp = Kbh + (size_t)tok * 64 + sg * 8;                 \
            PK0 = *(const uint4*)(kp);                                         \
            PK1 = *(const uint4*)(kp + 32);                                    \
            int t0 = min(start + pt + 8 * sg, total - 8);                      \
            int t1 = min(start + pt + 8 * sg + 32, total - 8);                 \
            const short* vp = Vbh + (size_t)sr * total;                        \
            PV0 = *(const uint4*)(vp + t0);                                    \
            PV1 = *(const uint4*)(vp + t1);                                    \
        }                                                                      \
        /* ---- S^T: 4 key-tiles of 16 (rows permuted) from read buf ---- */   \
        f4v s0 = {0,0,0,0}, s1 = {0,0,0,0}, s2 = {0,0,0,0}, s3 = {0,0,0,0};    \
        {                                                                      \
            bf8 ka, kb;                                                        \
            ka = *(const bf8*)&KR[(c     ) * KSTR + qd * 8];                   \
            kb = *(const bf8*)&KR[(c     ) * KSTR + 32 + qd * 8];              \
            __builtin_amdgcn_s_setprio(1);                                     \
            s0 = MFMA(ka, qf0.v, s0); s0 = MFMA(kb, qf1.v, s0);                \
            ka = *(const bf8*)&KR[(16 + c) * KSTR + qd * 8];                   \
            kb = *(const bf8*)&KR[(16 + c) * KSTR + 32 + qd * 8];              \
            s1 = MFMA(ka, qf0.v, s1); s1 = MFMA(kb, qf1.v, s1);                \
            ka = *(const bf8*)&KR[(32 + c) * KSTR + qd * 8];                   \
            kb = *(const bf8*)&KR[(32 + c) * KSTR + 32 + qd * 8];              \
            s2 = MFMA(ka, qf0.v, s2); s2 = MFMA(kb, qf1.v, s2);                \
            ka = *(const bf8*)&KR[(48 + c) * KSTR + qd * 8];                   \
            kb = *(const bf8*)&KR[(48 + c) * KSTR + 32 + qd * 8];              \
            s3 = MFMA(ka, qf0.v, s3); s3 = MFMA(kb, qf1.v, s3);                \
            __builtin_amdgcn_s_setprio(0);                                     \
        }                                                                      \
        /* element (j,qd,r) is key 32(j>>1)+8qd+4(j&1)+r */                    \
        float e[16];                                                           \
        _Pragma("unroll")                                                      \
        for (int r = 0; r < 4; ++r) {                                          \
            e[r] = s0[r]; e[4 + r] = s1[r]; e[8 + r] = s2[r]; e[12 + r] = s3[r];\
        }                                                                      \
        if (kt0 + 63 > q0) {                                                   \
            const int limit = q0 + c - kt0 - 8 * qd;                           \
            _Pragma("unroll")                                                  \
            for (int j = 0; j < 4; ++j) {                                      \
                const int kb_ = 32 * (j >> 1) + 4 * (j & 1);                   \
                _Pragma("unroll")                                              \
                for (int r = 0; r < 4; ++r)                                    \
                    if (kb_ + r > limit) e[4 * j + r] = NEGF;                  \
            }                                                                  \
        }                                                                      \
        float ls = 0.f;                                                        \
        _Pragma("unroll")                                                      \
        for (int i = 0; i < 16; ++i) { e[i] = exp2f(e[i]); ls += e[i]; }       \
        l_i += ls;                                                             \
        /* P fragments directly in registers (natural key order) */            \
        bf8u p0u, p1u;                                                         \
        p0u.w[0] = pk(e[0],  e[1]);  p0u.w[1] = pk(e[2],  e[3]);               \
        p0u.w[2] = pk(e[4],  e[5]);  p0u.w[3] = pk(e[6],  e[7]);               \
        p1u.w[0] = pk(e[8],  e[9]);  p1u.w[1] = pk(e[10], e[11]);              \
        p1u.w[2] = pk(e[12], e[13]); p1u.w[3] = pk(e[14], e[15]);              \
        bf8 p0 = p0u.v, p1 = p1u.v;                                            \
        /* O^T += V^T · P^T */                                                 \
        __builtin_amdgcn_s_setprio(1);                                         \
        o0 = MFMA(*(const bf8*)&VR[(c     ) * KSTR + qd * 8],      p0, o0);    \
        o0 = MFMA(*(const bf8*)&VR[(c     ) * KSTR + 32 + qd * 8], p1, o0);    \
        o1 = MFMA(*(const bf8*)&VR[(16 + c) * KSTR + qd * 8],      p0, o1);    \
        o1 = MFMA(*(const bf8*)&VR[(16 + c) * KSTR + 32 + qd * 8], p1, o1);    \
        o2 = MFMA(*(const bf8*)&VR[(32 + c) * KSTR + qd * 8],      p0, o2);    \
        o2 = MFMA(*(const bf8*)&VR[(32 + c) * KSTR + 32 + qd * 8], p1, o2);    \
        o3 = MFMA(*(const bf8*)&VR[(48 + c) * KSTR + qd * 8],      p0, o3);    \
        o3 = MFMA(*(const bf8*)&VR[(48 + c) * KSTR + 32 + qd * 8], p1, o3);    \
        __builtin_amdgcn_s_setprio(0);                                         \
        BARRIER_NOVM()                           /* end of iteration */        \
    }

// ---------- kernel B: attention ----------
__global__ __launch_bounds__(256, 4)
void attn16(const float* __restrict__ q, const short* __restrict__ Kb,
            const short* __restrict__ Vb, const int* __restrict__ cu,
            float* __restrict__ out, int nb, int total)
{
    __shared__ __attribute__((aligned(16))) short Ks[2][BN * KSTR];   // [buf][perm key][d]
    __shared__ __attribute__((aligned(16))) short Vt[2][D * KSTR];    // [buf][d][key]

    const int kvh = blockIdx.y;

    // locate (seq, q-tile); long tiles (high q0) first
    int bid = blockIdx.x, b = -1, start = 0, len = 0, q0 = 0, acc = 0;
    for (int i = 0; i < nb; ++i) {
        int s0 = cu[i], l = cu[i + 1] - s0, nt = (l + BM - 1) / BM;
        if (bid < acc + nt) { b = i; start = s0; len = l; q0 = (nt - 1 - (bid - acc)) * BM; break; }
        acc += nt;
    }
    if (b < 0) return;

    const int t = threadIdx.x, w = t >> 6, lane = t & 63;
    const int qd = lane >> 4, c = lane & 15;
    const int h = kvh * 4 + w;
    const int rows = min(BM, len - q0), kend = q0 + rows;
    const float SC = 0.125f * 1.44269504f;        // scale * log2(e)

    // ---- Q B-fragments straight from global (scaled) ----
    bf8u qf0, qf1;
    {
        int qr = min(c, rows - 1);
        const float* qp = q + (size_t)(start + q0 + qr) * (H * D) + h * D + qd * 8;
        float4 a0 = *(const float4*)qp;
        float4 a1 = *(const float4*)(qp + 4);
        float4 a2 = *(const float4*)(qp + 32);
        float4 a3 = *(const float4*)(qp + 36);
        qf0.w[0] = pk(a0.x * SC, a0.y * SC); qf0.w[1] = pk(a0.z * SC, a0.w * SC);
        qf0.w[2] = pk(a1.x * SC, a1.y * SC); qf0.w[3] = pk(a1.z * SC, a1.w * SC);
        qf1.w[0] = pk(a2.x * SC, a2.y * SC); qf1.w[1] = pk(a2.z * SC, a2.w * SC);
        qf1.w[2] = pk(a3.x * SC, a3.y * SC); qf1.w[3] = pk(a3.z * SC, a3.w * SC);
    }

    // staging roles: row sr (0..63), granules sg and sg+4 (8 bf16 = 16B each)
    const int sr = t >> 2, sg = t & 3;
    // permuted K row: key sr lands at row rho(sr) (swap bit2 <-> bits4:3)
    const int rs = (sr & 0x23) | ((sr & 0x18) >> 1) | ((sr & 4) << 2);
    const short* Kbh = Kb + (size_t)kvh * total * 64;
    const short* Vbh = Vb + (size_t)kvh * 64 * total;

    short* Ks0 = &Ks[0][0]; short* Vt0 = &Vt[0][0];
    short* Ks1 = &Ks[1][0]; short* Vt1 = &Vt[1][0];

    // two prefetch register sets (A stages even bufs, B stages odd)
    uint4 kpA0, kpA1, vpA0, vpA1;
    uint4 kpB0, kpB1, vpB0, vpB1;
    #define LOADSET(PK0, PK1, PV0, PV1, KT)                                    \
    {                                                                          \
        int tok = min(start + (KT) + sr, total - 1);                           \
        const short* kp = Kbh + (size_t)tok * 64 + sg * 8;                     \
        PK0 = *(const uint4*)(kp);                                             \
        PK1 = *(const uint4*)(kp + 32);                                        \
        int t0 = min(start + (KT) + 8 * sg, total - 8);                        \
        int t1 = min(start + (KT) + 8 * sg + 32, total - 8);                   \
        const short* vp = Vbh + (size_t)sr * total;                            \
        PV0 = *(const uint4*)(vp + t0);                                        \
        PV1 = *(const uint4*)(vp + t1);                                        \
    }

    LOADSET(kpA0, kpA1, vpA0, vpA1, 0)
    LOADSET(kpB0, kpB1, vpB0, vpB1, BN)

    // prologue: stage tile 0 into buf0 from A, refill A <- tile 2
    *(uint4*)&Ks0[rs * KSTR + sg * 8]      = kpA0;
    *(uint4*)&Ks0[rs * KSTR + sg * 8 + 32] = kpA1;
    *(uint4*)&Vt0[sr * KSTR + sg * 8]      = vpA0;
    *(uint4*)&Vt0[sr * KSTR + sg * 8 + 32] = vpA1;
    LOADSET(kpA0, kpA1, vpA0, vpA1, 2 * BN)
    BARRIER_NOVM()

    float l_i = 0.f;
    f4v o0 = {0,0,0,0}, o1 = {0,0,0,0}, o2 = {0,0,0,0}, o3 = {0,0,0,0};

    int kt0 = 0;
    for (;;) {
        // compute buf0 (tile kt0); stage buf1 <- B (tile kt0+BN); refill B
        ATTN_ITER(Ks0, Vt0, Ks1, Vt1, kpB0, kpB1, vpB0, vpB1)
        kt0 += BN; if (kt0 >= kend) break;
        // compute buf1; stage buf0 <- A (tile kt0+BN); refill A
        ATTN_ITER(Ks1, Vt1, Ks0, Vt0, kpA0, kpA1, vpA0, vpA1)
        kt0 += BN; if (kt0 >= kend) break;
    }

    // ---- epilogue: cross-lane l reduction (quads hold disjoint key sets) ----
    if (c < rows) {
        float lt = l_i + __shfl_xor(l_i, 16, 64);
        lt += __shfl_xor(lt, 32, 64);
        const float inv = 1.f / lt;
        float* op = out + (size_t)(start + q0 + c) * (H * D) + h * D + 4 * qd;
        *(float4*)(op)      = make_float4(o0[0] * inv, o0[1] * inv, o0[2] * inv, o0[3] * inv);
        *(float4*)(op + 16) = make_float4(o1[0] * inv, o1[1] * inv, o1[2] * inv, o1[3] * inv);
        *(float4*)(op + 32) = make_float4(o2[0] * inv, o2[1] * inv, o2[2] * inv, o2[3] * inv);
        *(float4*)(op + 48) = make_float4(o3[0] * inv, o3[1] * inv, o3[2] * inv, o3[3] * inv);
    }
}

extern "C" void kernel_launch(void* const* d_in, const int* in_sizes, int n_in,
                              void* d_out, int out_size, void* d_ws, size_t ws_size,
                              hipStream_t stream) {
    const float* q  = (const float*)d_in[0];
    const float* kv = (const float*)d_in[1];
    const int*   cu = (const int*)d_in[2];
    float* out = (float*)d_out;

    const int total = in_sizes[0] / (H * D);
    const int nb    = in_sizes[2] - 1;

    short* Kb = (short*)d_ws;                               // 4*total*64 bf16
    short* Vb = Kb + (size_t)HKV * total * 64;              // 4*total*64 bf16

    dim3 gridA((total + 63) / 64, HKV);
    preconv<<<gridA, 256, 0, stream>>>(kv, Kb, Vb, total);

    const int tile_ub = total / BM + nb;                    // >= sum of ceil(len/BM)
    dim3 gridB(tile_ub, HKV);
    attn16<<<gridB, 256, 0, stream>>>(q, Kb, Vb, cu, out, nb, total);
}